// Round 1
// 440.935 us; speedup vs baseline: 1.0632x; 1.0632x over previous
//
#include <hip/hip_runtime.h>

#define TT 256
#define BB 2048
#define DIN 128
#define DWROW 132           // D + H
#define INV2PI 0.15915494309189535f
#define LOG2E  1.4426950408889634f

__device__ __forceinline__ const float* rfl_ptr(const float* p) {
    unsigned long long u = (unsigned long long)p;
    unsigned lo = __builtin_amdgcn_readfirstlane((unsigned)u);
    unsigned hi = __builtin_amdgcn_readfirstlane((unsigned)(u >> 32));
    return (const float*)(((unsigned long long)hi << 32) | lo);
}

// quad broadcast via DPP: every lane of each 4-lane quad gets lane j's value.
// quad_perm[j,j,j,j] ctrl = j*0x55 -- symmetric, no shift-direction ambiguity.
#define DPP_BCAST(dst, src, j) \
    dst = __int_as_float(__builtin_amdgcn_update_dpp( \
        0, __float_as_int(src), (j) * 0x55, 0xF, 0xF, true))

// ds_swizzle BitMode (pull): dst lane i reads src lane ((i & and) | or).
// offset imm = (or<<5) | and, bit15=0.
#define SWZ(dst, src, imm) \
    dst = __int_as_float(__builtin_amdgcn_ds_swizzle(__float_as_int(src), (imm)))

__device__ __forceinline__ float tanh_f(float x) {
    float e = __builtin_amdgcn_exp2f((2.0f * LOG2E) * x);
    return 1.0f - 2.0f * __builtin_amdgcn_rcpf(1.0f + e);
}

// ---------------- Phase 1 (unchanged: near memory roofline) ----------------
// Ax[row][g*4+w] = (x[row,:] . W_g[w,:128] + b_g[w] + th_g[w]) * INV2PI
__global__ __launch_bounds__(256) void qlstm_phase1(
    const float* __restrict__ x,
    const float* __restrict__ Wf, const float* __restrict__ bf, const float* __restrict__ thf,
    const float* __restrict__ Wi, const float* __restrict__ bi, const float* __restrict__ thi,
    const float* __restrict__ Wu, const float* __restrict__ bu, const float* __restrict__ thu,
    const float* __restrict__ Wo, const float* __restrict__ bo, const float* __restrict__ tho,
    float* __restrict__ Ax)
{
    __shared__ float xT[DIN][65];

    const int tid = threadIdx.x;
    const size_t tile = blockIdx.x;

    const float4* xg = (const float4*)x + tile * (64 * DIN / 4);
#pragma unroll
    for (int i = 0; i < 8; ++i) {
        int f   = i * 256 + tid;
        int row = f >> 5;
        int c4  = f & 31;
        float4 v = xg[f];
        xT[4 * c4 + 0][row] = v.x;
        xT[4 * c4 + 1][row] = v.y;
        xT[4 * c4 + 2][row] = v.z;
        xT[4 * c4 + 3][row] = v.w;
    }
    __syncthreads();

    const int wv   = tid >> 6;
    const int lane = tid & 63;

    const float* Wp  = (wv == 0) ? Wf  : (wv == 1) ? Wi  : (wv == 2) ? Wu  : Wo;
    const float* bp  = (wv == 0) ? bf  : (wv == 1) ? bi  : (wv == 2) ? bu  : bo;
    const float* thp = (wv == 0) ? thf : (wv == 1) ? thi : (wv == 2) ? thu : tho;
    const float* Wg  = rfl_ptr(Wp);
    const float* bg  = rfl_ptr(bp);
    const float* thg = rfl_ptr(thp);

    float acc0 = bg[0] + thg[0];
    float acc1 = bg[1] + thg[1];
    float acc2 = bg[2] + thg[2];
    float acc3 = bg[3] + thg[3];

#pragma unroll 8
    for (int j = 0; j < DIN; ++j) {
        float xv = xT[j][lane];
        acc0 = fmaf(xv, Wg[0 * DWROW + j], acc0);
        acc1 = fmaf(xv, Wg[1 * DWROW + j], acc1);
        acc2 = fmaf(xv, Wg[2 * DWROW + j], acc2);
        acc3 = fmaf(xv, Wg[3 * DWROW + j], acc3);
    }

    float4 o;
    o.x = acc0 * INV2PI; o.y = acc1 * INV2PI;
    o.z = acc2 * INV2PI; o.w = acc3 * INV2PI;
    ((float4*)Ax)[(tile * 64 + lane) * 4 + wv] = o;
}

// ---------------- Phase 2: 16 lanes per batch element ----------------------
// lane = el*16 + g*4 + w  (g = gate f/i/u/o, w = wire). Each lane owns ONE
// (gate,wire) angle -> 1 cos + 1 activation per step (was 4 cos + 10 trans).
// Quad (4 wires of one gate): cos products + h broadcast via quad_perm DPP.
// Cross-gate act gather (stride 4 in the 16-group): ds_swizzle pull,
// src = (lane & 0b10011) | (g'<<2)  -> imm = (g'<<2)<<5 | 0x13.
__global__ __launch_bounds__(64) void qlstm_phase2(
    const float* __restrict__ Ax,
    const float* __restrict__ Wf, const float* __restrict__ Wi,
    const float* __restrict__ Wu, const float* __restrict__ Wo,
    float* __restrict__ out)
{
    const int gtid = blockIdx.x * 64 + threadIdx.x;   // 0 .. BB*16-1
    const int w = gtid & 3;                            // wire
    const int g = (gtid >> 2) & 3;                     // gate
    const int b = gtid >> 4;                           // batch element

    const float* Wrow = (g == 0) ? Wf : (g == 1) ? Wi : (g == 2) ? Wu : Wo;
    // h-part of this (gate,wire) row, pre-scaled by 1/2pi
    const float wh0 = Wrow[w * DWROW + DIN + 0] * INV2PI;
    const float wh1 = Wrow[w * DWROW + DIN + 1] * INV2PI;
    const float wh2 = Wrow[w * DWROW + DIN + 2] * INV2PI;
    const float wh3 = Wrow[w * DWROW + DIN + 3] * INV2PI;

    // uniform activation: act = A + B * rcp(1 + exp2(k*x))
    // sigmoid (f,i,o): A=0, B=1,  k=-log2e ; tanh (u): A=1, B=-2, k=2*log2e
    const float kk = (g == 2) ? (2.0f * LOG2E) : (-LOG2E);
    const float Aa = (g == 2) ? 1.0f : 0.0f;
    const float Bb = (g == 2) ? -2.0f : 1.0f;

    const size_t S = (size_t)BB * 16;                  // Ax floats per timestep
    const float* ap = Ax + (size_t)b * 16 + (g * 4 + w);

    // prefetch ring, depth 4 (one dword per lane; wave reads 256B contiguous)
    float ar[4];
#pragma unroll
    for (int d = 0; d < 4; ++d)
        ar[d] = ap[(size_t)d * S];

    float hv0 = 0.f, hv1 = 0.f, hv2 = 0.f, hv3 = 0.f;  // h[0..3] (shared)
    float cst = 0.f;                                   // c[w] (same across g)
    float h   = 0.f;                                   // h[w]

    for (int t4 = 0; t4 < TT / 4; ++t4) {
#pragma unroll
        for (int k = 0; k < 4; ++k) {
            const int t = 4 * t4 + k;
            float a = ar[k];
            int tn = t + 4; if (tn > TT - 1) tn = TT - 1;
            ar[k] = ap[(size_t)tn * S];

            // angle (revolutions) for this (gate,wire): short fma tree
            float m23 = fmaf(hv2, wh2, hv3 * wh3);
            float ang = fmaf(hv0, wh0, fmaf(hv1, wh1, a)) + m23;
            float z   = __builtin_amdgcn_cosf(ang);

            // share cos across the wire-quad of this gate
            float q0, q1, q2, q3;
            DPP_BCAST(q0, z, 0);
            DPP_BCAST(q1, z, 1);
            DPP_BCAST(q2, z, 2);
            DPP_BCAST(q3, z, 3);
            float t23 = q2 * q3;
            float p01 = q0 * q1;
            float G = (w == 0) ? q1 * t23
                    : (w == 1) ? p01
                    : (w == 2) ? p01 * q2
                    :            p01 * t23;

            // this lane's single activation
            float e   = __builtin_amdgcn_exp2f(kk * G);
            float act = fmaf(Bb, __builtin_amdgcn_rcpf(1.0f + e), Aa);

            // gather f,i,u,o for this wire (pull from gate g' lanes)
            float fa, ia, ua, oa;
            SWZ(fa, act, 0x013);   // g'=0
            SWZ(ia, act, 0x093);   // g'=1
            SWZ(ua, act, 0x113);   // g'=2
            SWZ(oa, act, 0x193);   // g'=3

            cst = fmaf(fa, cst, ia * ua);
            float th = tanh_f(cst);
            h = oa * th;

            if (g == 0)
                out[(size_t)t * (BB * 4) + b * 4 + w] = h;

            // share h across the wire-quad for next step's angles
            DPP_BCAST(hv0, h, 0);
            DPP_BCAST(hv1, h, 1);
            DPP_BCAST(hv2, h, 2);
            DPP_BCAST(hv3, h, 3);
        }
    }

    if (g == 0) {
        out[(size_t)TT * BB * 4 + b * 4 + w]          = h;
        out[(size_t)TT * BB * 4 + BB * 4 + b * 4 + w] = cst;
    }
}

extern "C" void kernel_launch(void* const* d_in, const int* in_sizes, int n_in,
                              void* d_out, int out_size, void* d_ws, size_t ws_size,
                              hipStream_t stream)
{
    const float* x   = (const float*)d_in[0];
    const float* Wf  = (const float*)d_in[1];
    const float* bf  = (const float*)d_in[2];
    const float* thf = (const float*)d_in[3];
    const float* Wi  = (const float*)d_in[4];
    const float* bi  = (const float*)d_in[5];
    const float* thi = (const float*)d_in[6];
    const float* Wu  = (const float*)d_in[7];
    const float* bu  = (const float*)d_in[8];
    const float* thu = (const float*)d_in[9];
    const float* Wo  = (const float*)d_in[10];
    const float* bo  = (const float*)d_in[11];
    const float* tho = (const float*)d_in[12];
    float* Ax   = (float*)d_ws;               // T*B*16 floats = 33.5 MB
    float* outp = (float*)d_out;

    qlstm_phase1<<<dim3((TT * BB) / 64), dim3(256), 0, stream>>>(
        x, Wf, bf, thf, Wi, bi, thi, Wu, bu, thu, Wo, bo, tho, Ax);
    qlstm_phase2<<<dim3((BB * 16) / 64), dim3(64), 0, stream>>>(
        Ax, Wf, Wi, Wu, Wo, outp);
}